// Round 11
// baseline (375.204 us; speedup 1.0000x reference)
//
#include <hip/hip_runtime.h>
#include <hip/hip_bf16.h>
#include <cstdint>
#include <cstddef>

#define DEVFN static __device__ __forceinline__

typedef __attribute__((ext_vector_type(8))) short bf16x8;
typedef __attribute__((ext_vector_type(4))) float f32x4;

static constexpr int kB = 8192;
static constexpr int kIN = 1024;
static constexpr int kH = 2048;

DEVFN unsigned short f32_to_bf16(float f) {
  union { float f; unsigned int u; } v; v.f = f;
  unsigned int x = v.u;
  x += 0x7fffu + ((x >> 16) & 1u);   // round-to-nearest-even
  return (unsigned short)(x >> 16);
}
DEVFN float bf16_to_f32(unsigned short u) {
  union { unsigned int u; float f; } v; v.u = (unsigned int)u << 16;
  return v.f;
}

// one fused cast pass: fp32 -> bf16 for all five panels (vec4 per thread)
__global__ void cast_all(const float* __restrict__ x, const float* __restrict__ Wx,
                         const float* __restrict__ Wh, const float* __restrict__ Uz,
                         const float* __restrict__ h,
                         unsigned short* __restrict__ xb, unsigned short* __restrict__ Wxb,
                         unsigned short* __restrict__ Wcat, unsigned short* __restrict__ Acat) {
  const long i = (long)blockIdx.x * blockDim.x + threadIdx.x;  // vec4 index
  const float* src; unsigned short* dst; int sh, stride, off; long li;
  if (i < 2097152L)      { li = i;            src = x;  dst = xb;   sh = 8; stride = 1024; off = 0; }
  else if (i < 2621440L) { li = i - 2097152L; src = Wx; dst = Wxb;  sh = 8; stride = 1024; off = 0; }
  else if (i < 3670016L) { li = i - 2621440L; src = Wh; dst = Wcat; sh = 9; stride = 4096; off = 0; }
  else if (i < 4718592L) { li = i - 3670016L; src = Uz; dst = Wcat; sh = 9; stride = 4096; off = 2048; }
  else                   { li = i - 4718592L; src = h;  dst = Acat; sh = 9; stride = 4096; off = 0; }
  float4 v = *(const float4*)(src + li * 4);
  const long row = li >> sh;
  const long col = (li & ((1L << sh) - 1)) * 4;
  unsigned short* d = dst + row * stride + off + col;
  ushort4 o;
  o.x = f32_to_bf16(v.x); o.y = f32_to_bf16(v.y);
  o.z = f32_to_bf16(v.z); o.w = f32_to_bf16(v.w);
  *(ushort4*)d = o;
}

typedef const __attribute__((address_space(1))) unsigned int* gptr_t;
typedef __attribute__((address_space(3))) unsigned int* lptr_t;
DEVFN void gload16(const unsigned short* g, unsigned short* l) {
  // imm-offset arg applies to BOTH global and LDS addresses (r9 NaN bug): keep 0.
  __builtin_amdgcn_global_load_lds((gptr_t)g, (lptr_t)l, 16, 0, 0);
}

DEVFN void bar() { __builtin_amdgcn_s_barrier(); }
#define VMC0() asm volatile("s_waitcnt vmcnt(0)" ::: "memory")
#define VMC4() asm volatile("s_waitcnt vmcnt(4)" ::: "memory")
#define VMC6() asm volatile("s_waitcnt vmcnt(6)" ::: "memory")

// LDS geometry:
//   A regions: elems [0, 32768):      (buf*2 + half)*8192
//   B regions: elems [32768, 65536):  32768 + (buf*2 + half)*8192
// Swizzle: elem col stored at c ^ ((row&7)*8); row&7 == lr&7 thread-constant
// -> folds into per-thread base; all reads = base + compile-time literal.
// global_load_lds writes LINEAR; global SOURCE col pre-swizzled (rule 21).
//
// B-DOUBLE-BANKED schedule (this round): all B fragments read 2-4 phases
// ahead into the alternate bank (bE = even tiles, bO = odd tiles); stages
// perfectly balanced 2 gloads/phase; everything staged in pair j is pair
// j+1's data.
//   reads : ph1 aHi(b0)+bO.n0 | ph2 bO.n1, post A1(b0) | ph3 bO.n2
//           ph4 bO.n3, post aLo(b1) | ph5 aHi(b1)+bE.n0 | ph6 bE.n1, post A1(b1)
//           ph7 bE.n2 | ph8 bE.n3, post aLo(b0')
//   stages: ph1 B0'h0 | ph2 B0'h1 | ph3 A0'h0 | ph4 A0'h1
//           ph5 B1'h0 | ph6 B1'h1 | ph7 A1'h0 | ph8 A1'h1      (all @+128/+192)
//   drains: VMC6@ph3 (completes A1' of prev pair, age 3-4 ph; needed ph4 aLo)
//           VMC4@ph4 (completes B0' ph1-2, age 2-3; needed ph5 bE reads)
//           VMC6@ph7 (completes A0' ph3-4; needed ph8 aLo)
//           VMC4@ph8 (completes B1' ph5-6; needed next-ph1 bO reads)
//   Region-overwrite audit: every STAGE lands >=1 barrier after the region's
//   last ds_read (B0'@ph1 after prev-ph8 bE.n3 + 2 bars; A0'@ph3 after ph2
//   A1(b0) + 1 bar; B1'@ph5 after ph4 bO.n3 + 2 bars; A1'@ph7 after ph6
//   A1(b1) + 1 bar).

template<int BUF, int QM, int MI0, int MI1>
DEVFN void ldA(bf16x8 (&a)[4][2], const unsigned short* LA0, const unsigned short* LA1) {
#pragma unroll
  for (int mi = MI0; mi < MI1; ++mi) {
    a[mi][0] = *(const bf16x8*)(LA0 + BUF * 16384 + QM * 4096 + mi * 1024);
    a[mi][1] = *(const bf16x8*)(LA1 + BUF * 16384 + QM * 4096 + mi * 1024);
  }
}

// single B n-tile (2 x b128) into the given bank
template<int BUF, int N>
DEVFN void ldB1(bf16x8 (&bx)[4][2], const unsigned short* LB0, const unsigned short* LB1) {
  bx[N][0] = *(const bf16x8*)(LB0 + BUF * 16384 + N * 1024);
  bx[N][1] = *(const bf16x8*)(LB1 + BUF * 16384 + N * 1024);
}

template<int QM, int QN>
DEVFN void mfmaQ(f32x4 (&acc)[8][4], bf16x8 (&a)[4][2], bf16x8 (&bx)[4][2]) {
  __builtin_amdgcn_s_setprio(1);
#pragma unroll
  for (int kk = 0; kk < 2; ++kk)
#pragma unroll
    for (int mi = 0; mi < 4; ++mi)
#pragma unroll
      for (int ni = 0; ni < 2; ++ni)
        acc[QM * 4 + mi][QN * 2 + ni] = __builtin_amdgcn_mfma_f32_16x16x32_bf16(
            a[mi][kk], bx[QN * 2 + ni][kk], acc[QM * 4 + mi][QN * 2 + ni], 0, 0, 0);
  __builtin_amdgcn_s_setprio(0);
}

// C = A (MxK) * W^T (W NxK); bias per col.
//  EPI==0: zOut = bf16(tanh(.)) via LDS-repack coalesced store
//  EPI==1: u = sigmoid(.); out = u*h + (1-u)*z, h/z read bf16 from hzBuf
template<int EPI>
__global__ __launch_bounds__(512, 1)
void gemm256(const unsigned short* __restrict__ A,
             const unsigned short* __restrict__ W,
             const float* __restrict__ bias,
             int M, int K,
             unsigned short* __restrict__ zOut,
             const unsigned short* __restrict__ hzBuf, int ldhz,
             float* __restrict__ out, int ldo)
{
  __shared__ unsigned short lds[8][8192];
  unsigned short* L = &lds[0][0];

  const int nTM = M >> 8;
  const int bm = blockIdx.x % nTM, bn = blockIdx.x / nTM;
  const int rowBase = bm << 8, colBase = bn << 8;

  const int t = threadIdx.x;
  const int l = t & 63;
  const int w = t >> 6;
  const int lr = l & 15, lg = l >> 4;
  const int wm = w >> 2, wn = w & 3;

  // per-thread LDS read bases (swizzle folded in; second k-half = ^32 elems)
  const int kel0 = (lg * 8) ^ ((lr & 7) * 8);
  const unsigned short* LA0 = L + wm * 8192 + lr * 64 + kel0;
  const unsigned short* LA1 = L + wm * 8192 + lr * 64 + (kel0 ^ 32);
  const unsigned short* LB0 = L + 32768 + (wn >> 1) * 8192 + (wn & 1) * 4096 + lr * 64 + kel0;
  const unsigned short* LB1 = L + 32768 + (wn >> 1) * 8192 + (wn & 1) * 4096 + lr * 64 + (kel0 ^ 32);

  // staging: thread t covers lds elems [t*8, t*8+8) of each 8KB slab
  const int srow = t >> 3;                       // 0..63
  const int scol = (t & 7) * 8;                  // 0..56
  const int kcSrc = scol ^ ((srow & 7) * 8);     // inverse-swizzled source col
  const unsigned short* pa0 = A + (size_t)(rowBase + srow) * K + kcSrc;
  const unsigned short* pa1 = pa0 + (size_t)64 * K;
  const unsigned short* pa2 = pa0 + (size_t)128 * K;
  const unsigned short* pa3 = pa0 + (size_t)192 * K;
  const unsigned short* pb0 = W + (size_t)(colBase + srow) * K + kcSrc;
  const unsigned short* pb1 = pb0 + (size_t)64 * K;
  const unsigned short* pb2 = pb0 + (size_t)128 * K;
  const unsigned short* pb3 = pb0 + (size_t)192 * K;

  unsigned short* const sd = L + w * 512;
#define STAGE(P0, P1, BUF, OP, HALF, OFSE) do {                                \
    unsigned short* ld = sd + (OP) * 32768 + ((BUF) * 2 + (HALF)) * 8192;      \
    gload16((P0) + (OFSE), ld);                                                \
    gload16((P1) + (OFSE), ld + 4096);                                         \
  } while (0)

  f32x4 acc[8][4] = {};
  bf16x8 a[4][2], bE[4][2], bO[4][2];

  // prologue: stage buf0 = pair0-tile0 (+0) and buf1 = pair0-tile1 (+64)
  STAGE(pb0, pb1, 0, 1, 0, 0);  STAGE(pb2, pb3, 0, 1, 1, 0);
  STAGE(pa0, pa1, 0, 0, 0, 0);  STAGE(pa2, pa3, 0, 0, 1, 0);
  STAGE(pb0, pb1, 1, 1, 0, 64); STAGE(pb2, pb3, 1, 1, 1, 64);
  STAGE(pa0, pa1, 1, 0, 0, 64); STAGE(pa2, pa3, 1, 0, 1, 64);
  VMC0();
  bar();
  ldA<0, 0, 0, 2>(a, LA0, LA1);          // aLo(b0)
  ldB1<0, 0>(bE, LB0, LB1); ldB1<0, 1>(bE, LB0, LB1);
  ldB1<0, 2>(bE, LB0, LB1); ldB1<0, 3>(bE, LB0, LB1);

  const int NP = K >> 7;   // pairs of BK=64 K-tiles
  for (int j = 0; j < NP - 1; ++j) {
    // ph1: Q00-b0.  rd aHi(b0) + bO.n0(b1).  stage B0'h0.
    ldA<0, 0, 2, 4>(a, LA0, LA1);
    ldB1<1, 0>(bO, LB0, LB1);
    STAGE(pb0, pb1, 0, 1, 0, 128);
    bar();
    mfmaQ<0, 0>(acc, a, bE);
    bar();
    // ph2: Q01-b0.  rd bO.n1.  stage B0'h1.  post: a <- A1(b0).
    ldB1<1, 1>(bO, LB0, LB1);
    STAGE(pb2, pb3, 0, 1, 1, 128);
    bar();
    mfmaQ<0, 1>(acc, a, bE);
    ldA<0, 1, 0, 4>(a, LA0, LA1);
    bar();
    // ph3: Q10-b0.  rd bO.n2.  stage A0'h0.  VMC6: completes A1' (prev ph7-8).
    ldB1<1, 2>(bO, LB0, LB1);
    STAGE(pa0, pa1, 0, 0, 0, 128);
    bar();
    mfmaQ<1, 0>(acc, a, bE);
    VMC6();
    bar();
    // ph4: Q11-b0.  rd bO.n3.  stage A0'h1.  VMC4: completes B0' (ph1-2).
    //      post: aLo <- A0(b1) (buf1-A resident: staged prev ph7-8, drained ph3).
    ldB1<1, 3>(bO, LB0, LB1);
    STAGE(pa2, pa3, 0, 0, 1, 128);
    bar();
    mfmaQ<1, 1>(acc, a, bE);
    VMC4();
    ldA<1, 0, 0, 2>(a, LA0, LA1);
    bar();
    // ph5: Q00-b1.  rd aHi(b1) + bE.n0(b0').  stage B1'h0.
    ldA<1, 0, 2, 4>(a, LA0, LA1);
    ldB1<0, 0>(bE, LB0, LB1);
    STAGE(pb0, pb1, 1, 1, 0, 192);
    bar();
    mfmaQ<0, 0>(acc, a, bO);
    bar();
    // ph6: Q01-b1.  rd bE.n1.  stage B1'h1.  post: a <- A1(b1).
    ldB1<0, 1>(bE, LB0, LB1);
    STAGE(pb2, pb3, 1, 1, 1, 192);
    bar();
    mfmaQ<0, 1>(acc, a, bO);
    ldA<1, 1, 0, 4>(a, LA0, LA1);
    bar();
    // ph7: Q10-b1.  rd bE.n2.  stage A1'h0.  VMC6: completes A0' (ph3-4).
    ldB1<0, 2>(bE, LB0, LB1);
    STAGE(pa0, pa1, 1, 0, 0, 192);
    bar();
    mfmaQ<1, 0>(acc, a, bO);
    VMC6();
    bar();
    // ph8: Q11-b1.  rd bE.n3.  stage A1'h1.  VMC4: completes B1' (ph5-6).
    //      post: aLo <- A0(b0') (buf0-A staged ph3-4, drained ph7).
    ldB1<0, 3>(bE, LB0, LB1);
    STAGE(pa2, pa3, 1, 0, 1, 192);
    bar();
    mfmaQ<1, 1>(acc, a, bO);
    VMC4();
    ldA<0, 0, 0, 2>(a, LA0, LA1);
    bar();
    pa0 += 128; pa1 += 128; pa2 += 128; pa3 += 128;
    pb0 += 128; pb1 += 128; pb2 += 128; pb3 += 128;
  }
  // ---- peeled last pair: no stages; VMC0 at ph3; no bE/next reads ----
  {
    // ph1
    ldA<0, 0, 2, 4>(a, LA0, LA1);
    ldB1<1, 0>(bO, LB0, LB1);
    bar();
    mfmaQ<0, 0>(acc, a, bE);
    bar();
    // ph2
    ldB1<1, 1>(bO, LB0, LB1);
    bar();
    mfmaQ<0, 1>(acc, a, bE);
    ldA<0, 1, 0, 4>(a, LA0, LA1);
    bar();
    // ph3: VMC0 retires prev ph5-8 stages (ages 3-6 phases)
    ldB1<1, 2>(bO, LB0, LB1);
    bar();
    mfmaQ<1, 0>(acc, a, bE);
    VMC0();
    bar();
    // ph4
    ldB1<1, 3>(bO, LB0, LB1);
    bar();
    mfmaQ<1, 1>(acc, a, bE);
    ldA<1, 0, 0, 2>(a, LA0, LA1);
    bar();
    // ph5
    ldA<1, 0, 2, 4>(a, LA0, LA1);
    bar();
    mfmaQ<0, 0>(acc, a, bO);
    bar();
    // ph6
    bar();
    mfmaQ<0, 1>(acc, a, bO);
    ldA<1, 1, 0, 4>(a, LA0, LA1);
    bar();
    // ph7
    bar();
    mfmaQ<1, 0>(acc, a, bO);
    bar();
    // ph8
    bar();
    mfmaQ<1, 1>(acc, a, bO);
    bar();
  }
#undef STAGE

  if (EPI == 0) {
    // repack epilogue: acc -> LDS (swizzled bf16) -> coalesced 16B stores
    unsigned short* Z = L;   // 256x256 bf16 = 128 KiB
#pragma unroll
    for (int m = 0; m < 8; ++m) {
      const int rl = wm * 128 + m * 16 + lg * 4;
#pragma unroll
      for (int n = 0; n < 4; ++n) {
        const int cl = wn * 64 + n * 16 + lr;
        const float bs = bias[colBase + cl];
#pragma unroll
        for (int q = 0; q < 4; ++q) {
          const int r = rl + q;
          const int sc = cl ^ ((r & 7) * 8);
          Z[r * 256 + sc] = f32_to_bf16(tanhf(acc[m][n][q] + bs));
        }
      }
    }
    bar();
#pragma unroll
    for (int s = 0; s < 16; ++s) {
      const int gofs = (s * 512 + t) * 8;
      const int row = gofs >> 8;
      const int c0 = gofs & 255;
      const int sc0 = c0 ^ ((row & 7) * 8);
      bf16x8 v = *(const bf16x8*)(Z + row * 256 + sc0);
      *(bf16x8*)(zOut + (size_t)(rowBase + row) * ldhz + colBase + c0) = v;
    }
  } else {
    // C/D layout: col = lane&15, row = (lane>>4)*4 + reg  [HW-verified]
#pragma unroll
    for (int m = 0; m < 8; ++m) {
      const int r0 = rowBase + wm * 128 + m * 16 + lg * 4;
#pragma unroll
      for (int n = 0; n < 4; ++n) {
        const int c = colBase + wn * 64 + n * 16 + lr;
        const float bs = bias[c];
#pragma unroll
        for (int q = 0; q < 4; ++q) {
          const int r = r0 + q;
          const float pre = acc[m][n][q] + bs;
          const float u = 1.0f / (1.0f + __expf(-pre));
          const float hv = bf16_to_f32(hzBuf[(size_t)r * ldhz + c]);
          const float zv = bf16_to_f32(hzBuf[(size_t)r * ldhz + 2048 + c]);
          out[(size_t)r * ldo + c] = u * hv + (1.0f - u) * zv;
        }
      }
    }
  }
}

extern "C" void kernel_launch(void* const* d_in, const int* in_sizes, int n_in,
                              void* d_out, int out_size, void* d_ws, size_t ws_size,
                              hipStream_t stream) {
  const float* h  = (const float*)d_in[0];   // (B,H)
  const float* x  = (const float*)d_in[1];   // (B,IN)
  const float* Wx = (const float*)d_in[2];   // (H,IN)
  const float* bx = (const float*)d_in[3];   // (H)
  const float* Wh = (const float*)d_in[4];   // (H,H)
  const float* Uz = (const float*)d_in[5];   // (H,H)
  const float* bu = (const float*)d_in[6];   // (H)
  float* out = (float*)d_out;

  unsigned short* ws   = (unsigned short*)d_ws;
  unsigned short* xb   = ws;                          // B*IN
  unsigned short* Wxb  = xb + (size_t)kB * kIN;       // H*IN
  unsigned short* Wcat = Wxb + (size_t)kH * kIN;      // H*2H  ([Wh|Uz])
  unsigned short* Acat = Wcat + (size_t)kH * 2 * kH;  // B*2H  ([h|z])

  cast_all<<<34816, 256, 0, stream>>>(x, Wx, Wh, Uz, h, xb, Wxb, Wcat, Acat);

  const int grid = (kB / 256) * (kH / 256);  // 256 = 1 block/CU

  // GEMM1: z = tanh(x Wx^T + bx) -> bf16 into Acat[:, H:2H]
  gemm256<0><<<grid, 512, 0, stream>>>(
      xb, Wxb, bx, kB, kIN, Acat + kH, nullptr, 2 * kH, nullptr, 0);

  // GEMM2: u = sigmoid([h|z] [Wh|Uz]^T + bu); out = u*h + (1-u)*z (h,z bf16)
  gemm256<1><<<grid, 512, 0, stream>>>(
      Acat, Wcat, bu, kB, 2 * kH, nullptr, Acat, 2 * kH, out, kH);
}

// Round 12
// 206.205 us; speedup vs baseline: 1.8196x; 1.8196x over previous
//
#include <hip/hip_runtime.h>
#include <hip/hip_bf16.h>
#include <cstdint>
#include <cstddef>

#define DEVFN static __device__ __forceinline__

typedef __attribute__((ext_vector_type(8))) short bf16x8;
typedef __attribute__((ext_vector_type(4))) float f32x4;

static constexpr int kB = 8192;
static constexpr int kIN = 1024;
static constexpr int kH = 2048;

DEVFN unsigned short f32_to_bf16(float f) {
  union { float f; unsigned int u; } v; v.f = f;
  unsigned int x = v.u;
  x += 0x7fffu + ((x >> 16) & 1u);   // round-to-nearest-even
  return (unsigned short)(x >> 16);
}
DEVFN float bf16_to_f32(unsigned short u) {
  union { unsigned int u; float f; } v; v.u = (unsigned int)u << 16;
  return v.f;
}

// one fused cast pass: fp32 -> bf16 for all five panels (vec4 per thread)
__global__ void cast_all(const float* __restrict__ x, const float* __restrict__ Wx,
                         const float* __restrict__ Wh, const float* __restrict__ Uz,
                         const float* __restrict__ h,
                         unsigned short* __restrict__ xb, unsigned short* __restrict__ Wxb,
                         unsigned short* __restrict__ Wcat, unsigned short* __restrict__ Acat) {
  const long i = (long)blockIdx.x * blockDim.x + threadIdx.x;  // vec4 index
  const float* src; unsigned short* dst; int sh, stride, off; long li;
  if (i < 2097152L)      { li = i;            src = x;  dst = xb;   sh = 8; stride = 1024; off = 0; }
  else if (i < 2621440L) { li = i - 2097152L; src = Wx; dst = Wxb;  sh = 8; stride = 1024; off = 0; }
  else if (i < 3670016L) { li = i - 2621440L; src = Wh; dst = Wcat; sh = 9; stride = 4096; off = 0; }
  else if (i < 4718592L) { li = i - 3670016L; src = Uz; dst = Wcat; sh = 9; stride = 4096; off = 2048; }
  else                   { li = i - 4718592L; src = h;  dst = Acat; sh = 9; stride = 4096; off = 0; }
  float4 v = *(const float4*)(src + li * 4);
  const long row = li >> sh;
  const long col = (li & ((1L << sh) - 1)) * 4;
  unsigned short* d = dst + row * stride + off + col;
  ushort4 o;
  o.x = f32_to_bf16(v.x); o.y = f32_to_bf16(v.y);
  o.z = f32_to_bf16(v.z); o.w = f32_to_bf16(v.w);
  *(ushort4*)d = o;
}

typedef const __attribute__((address_space(1))) unsigned int* gptr_t;
typedef __attribute__((address_space(3))) unsigned int* lptr_t;
DEVFN void gload16(const unsigned short* g, unsigned short* l) {
  __builtin_amdgcn_global_load_lds((gptr_t)g, (lptr_t)l, 16, 0, 0);
}

DEVFN void bar() { __builtin_amdgcn_s_barrier(); }
#define VMC0() asm volatile("s_waitcnt vmcnt(0)" ::: "memory")
#define VMC2() asm volatile("s_waitcnt vmcnt(2)" ::: "memory")

// LDS geometry: 8 regions of [128 rows][64 bf16] (16 KiB each) = 128 KiB.
// region = buf*4 + op*2 + half   (op: 0=A, 1=B; half: rows 0-127 / 128-255)
// Swizzle (T2): element col stored at  c ^ ((row&7)*8).
// global_load_lds writes LINEAR; global SOURCE col is pre-swizzled (rule 21).
//
// ONE-PHASE-AHEAD fragment pipeline (best-measured structure, r7 bench):
//   quadrant order per K-tile: Q00,Q01,Q10,Q11.  Single a[4][2] bank,
//   reloaded POST-MFMA at ph2/4/6/8 (WAR-safe: after last use);
//   b halves reloaded PRE-MFMA at ph1/4/5/8.  Every read issued >=1 phase
//   before its consuming MFMA; NO manual lgkmcnt (compiler inserts minimal
//   counted waits so LDS reads overlap MFMA).
//   Stage plan (2 gloads/phase; ph8 has 4):
//     ph1=A1h1(2j+1), ph3=B0'h0, ph4=B0'h1, ph5=A0'h0, ph6=A0'h1,
//     ph7=B1'h0, ph8=B1'h1+A1'h0            (buf0'=2j+2, buf1'=2j+3)
//   Drains: vmcnt(2) at ph3-end (retires buf1' = ph7,ph8 prev + ph1) and
//   vmcnt(2) at ph7-end (retires buf0' = ph3..ph6).  Never vmcnt(0),
//   never drain a same-phase load.

template<int BUF, int QM>
DEVFN void ldA(bf16x8 (&a)[4][2], const unsigned short* lds, int wm, int lr, int lg) {
  const unsigned short* rg = lds + (size_t)(BUF * 4 + wm) * 8192;
#pragma unroll
  for (int mi = 0; mi < 4; ++mi) {
    const int rl = QM * 64 + mi * 16 + lr;
#pragma unroll
    for (int kk = 0; kk < 2; ++kk) {
      const int kel = (kk * 32 + lg * 8) ^ ((rl & 7) * 8);
      a[mi][kk] = *(const bf16x8*)(rg + rl * 64 + kel);
    }
  }
}

template<int BUF, int QN>
DEVFN void ldB(bf16x8 (&b)[4][2], const unsigned short* lds, int wn, int lr, int lg) {
  const unsigned short* rg = lds + (size_t)(BUF * 4 + 2 + (wn >> 1)) * 8192;
#pragma unroll
  for (int ni = 0; ni < 2; ++ni) {
    const int n = QN * 2 + ni;
    const int cl = (wn & 1) * 64 + n * 16 + lr;
#pragma unroll
    for (int kk = 0; kk < 2; ++kk) {
      const int kel = (kk * 32 + lg * 8) ^ ((cl & 7) * 8);
      b[n][kk] = *(const bf16x8*)(rg + cl * 64 + kel);
    }
  }
}

template<int QM, int QN>
DEVFN void mfmaQ(f32x4 (&acc)[8][4], bf16x8 (&a)[4][2], bf16x8 (&b)[4][2]) {
  __builtin_amdgcn_s_setprio(1);
#pragma unroll
  for (int mi = 0; mi < 4; ++mi)
#pragma unroll
    for (int ni = 0; ni < 2; ++ni)
#pragma unroll
      for (int kk = 0; kk < 2; ++kk)
        acc[QM * 4 + mi][QN * 2 + ni] = __builtin_amdgcn_mfma_f32_16x16x32_bf16(
            a[mi][kk], b[QN * 2 + ni][kk], acc[QM * 4 + mi][QN * 2 + ni], 0, 0, 0);
  __builtin_amdgcn_s_setprio(0);
}

// C = A (MxK) * W^T (W NxK); bias per col.
//  EPI==0: zOut = bf16(tanh(.))           (zOut = Acat z-half, ldhz stride)
//  EPI==1: u = sigmoid(.); out = u*h + (1-u)*z, h/z read bf16 from hzBuf
template<int EPI>
__global__ __launch_bounds__(512, 1)
void gemm256(const unsigned short* __restrict__ A,
             const unsigned short* __restrict__ W,
             const float* __restrict__ bias,
             int M, int K,
             unsigned short* __restrict__ zOut,
             const unsigned short* __restrict__ hzBuf, int ldhz,
             float* __restrict__ out, int ldo)
{
  __shared__ unsigned short lds[8][8192];
  unsigned short* L = &lds[0][0];

  const int nTM = M >> 8;
  const int bm = blockIdx.x % nTM, bn = blockIdx.x / nTM;
  const int rowBase = bm << 8, colBase = bn << 8;

  const int t = threadIdx.x;
  const int l = t & 63;
  const int w = t >> 6;
  const int lr = l & 15, lg = l >> 4;
  const int wm = w >> 2, wn = w & 3;

  // staging addresses: thread t covers lds elems [t*8, t*8+8) of each 8KB slab
  const int srow = t >> 3;                       // 0..63
  const int scol = (t & 7) * 8;                  // 0..56
  const int kcSrc = scol ^ ((srow & 7) * 8);     // inverse-swizzled source col
  const unsigned short* gA = A + (size_t)(rowBase + srow) * K + kcSrc;
  const unsigned short* gB = W + (size_t)(colBase + srow) * K + kcSrc;

  // STAGE(buf, op, half, kt): one 16KB half-tile, 2 x global_load_lds per thread
#define STAGE(BUF, OP, HALF, KT) do {                                          \
    const unsigned short* gs = ((OP) ? gB : gA)                                \
        + (size_t)((HALF) * 128) * K + (size_t)(KT) * 64;                      \
    unsigned short* ld = L + (size_t)((BUF) * 4 + (OP) * 2 + (HALF)) * 8192    \
        + w * 512;                                                             \
    gload16(gs, ld);                                                           \
    gload16(gs + (size_t)64 * K, ld + 4096);                                   \
  } while (0)

  f32x4 acc[8][4] = {};
  bf16x8 a[4][2], b[4][2];

  // prologue: stage buf0=tile0, buf1=tile1 fully; drain; preload a=A0b0, b01=B0b0
  STAGE(0, 1, 0, 0); STAGE(0, 1, 1, 0); STAGE(0, 0, 0, 0); STAGE(0, 0, 1, 0);
  STAGE(1, 1, 0, 1); STAGE(1, 1, 1, 1); STAGE(1, 0, 0, 1); STAGE(1, 0, 1, 1);
  VMC0();
  bar();
  ldA<0, 0>(a, L, wm, lr, lg);
  ldB<0, 0>(b, L, wn, lr, lg);

  const int NP = K >> 7;   // pairs of BK=64 K-tiles
  for (int j = 0; j < NP; ++j) {
    const bool more = (j + 1 < NP);
    const int ktb1 = 2 * j + 1;                     // buf1-A h1 (this pair; j=0: benign rewrite)
    const int kt0n = more ? 2 * j + 2 : 2 * j;      // buf0' (clamped: benign identical restage)
    const int kt1n = more ? 2 * j + 3 : 2 * j + 1;  // buf1' (clamped)

    // ph1: Q00-b0.  pre: B1b0 -> b23 (used ph2/ph4).  stage A1h1.
    ldB<0, 1>(b, L, wn, lr, lg);
    STAGE(1, 0, 1, ktb1);
    bar();
    mfmaQ<0, 0>(acc, a, b);
    bar();
    // ph2: Q01-b0.  post: a <- A1b0 (used ph3/ph4; WAR-safe after MFMA).
    bar();
    mfmaQ<0, 1>(acc, a, b);
    ldA<0, 1>(a, L, wm, lr, lg);
    bar();
    // ph3: Q10-b0.  stage B0'h0.  drain buf1' (ph7/ph8 prev + ph1) = vmcnt(2).
    STAGE(0, 1, 0, kt0n);
    bar();
    mfmaQ<1, 0>(acc, a, b);
    VMC2();
    bar();
    // ph4: Q11-b0.  pre: B0b1 -> b01 (b01 dead after ph3; used ph5/ph7).
    //      stage B0'h1.  post: a <- A0b1 (buf1 resident since ph3 drain).
    ldB<1, 0>(b, L, wn, lr, lg);
    STAGE(0, 1, 1, kt0n);
    bar();
    mfmaQ<1, 1>(acc, a, b);
    ldA<1, 0>(a, L, wm, lr, lg);
    bar();
    // ph5: Q00-b1.  pre: B1b1 -> b23 (dead after ph4; used ph6/ph8).  stage A0'h0.
    ldB<1, 1>(b, L, wn, lr, lg);
    STAGE(0, 0, 0, kt0n);
    bar();
    mfmaQ<0, 0>(acc, a, b);
    bar();
    // ph6: Q01-b1.  stage A0'h1.  post: a <- A1b1 (used ph7/ph8).
    STAGE(0, 0, 1, kt0n);
    bar();
    mfmaQ<0, 1>(acc, a, b);
    ldA<1, 1>(a, L, wm, lr, lg);
    bar();
    // ph7: Q10-b1.  stage B1'h0.  drain buf0' (ph3..ph6) = vmcnt(2).
    STAGE(1, 1, 0, kt1n);
    bar();
    mfmaQ<1, 0>(acc, a, b);
    VMC2();
    bar();
    // ph8: Q11-b1.  pre: B0 of next pair -> b01 (b01 dead after ph7; buf0'
    //      drained at ph7).  stage B1'h1 + A1'h0.  post: a <- A0 next pair.
    ldB<0, 0>(b, L, wn, lr, lg);
    STAGE(1, 1, 1, kt1n);
    STAGE(1, 0, 0, kt1n);
    bar();
    mfmaQ<1, 1>(acc, a, b);
    ldA<0, 0>(a, L, wm, lr, lg);
    bar();
  }
#undef STAGE

  // epilogue; C/D layout: col = lane&15, row = (lane>>4)*4 + reg  [HW-verified]
#pragma unroll
  for (int m = 0; m < 8; ++m) {
    const int r0 = rowBase + wm * 128 + m * 16 + lg * 4;
#pragma unroll
    for (int n = 0; n < 4; ++n) {
      const int c = colBase + wn * 64 + n * 16 + lr;
      const float bs = bias[c];
#pragma unroll
      for (int q = 0; q < 4; ++q) {
        const int r = r0 + q;
        const float pre = acc[m][n][q] + bs;
        if (EPI == 0) {
          zOut[(size_t)r * ldhz + c] = f32_to_bf16(tanhf(pre));
        } else {
          const float u = 1.0f / (1.0f + __expf(-pre));
          const float hv = bf16_to_f32(hzBuf[(size_t)r * ldhz + c]);
          const float zv = bf16_to_f32(hzBuf[(size_t)r * ldhz + 2048 + c]);
          out[(size_t)r * ldo + c] = u * hv + (1.0f - u) * zv;
        }
      }
    }
  }
}

extern "C" void kernel_launch(void* const* d_in, const int* in_sizes, int n_in,
                              void* d_out, int out_size, void* d_ws, size_t ws_size,
                              hipStream_t stream) {
  const float* h  = (const float*)d_in[0];   // (B,H)
  const float* x  = (const float*)d_in[1];   // (B,IN)
  const float* Wx = (const float*)d_in[2];   // (H,IN)
  const float* bx = (const float*)d_in[3];   // (H)
  const float* Wh = (const float*)d_in[4];   // (H,H)
  const float* Uz = (const float*)d_in[5];   // (H,H)
  const float* bu = (const float*)d_in[6];   // (H)
  float* out = (float*)d_out;

  unsigned short* ws   = (unsigned short*)d_ws;
  unsigned short* xb   = ws;                          // B*IN
  unsigned short* Wxb  = xb + (size_t)kB * kIN;       // H*IN
  unsigned short* Wcat = Wxb + (size_t)kH * kIN;      // H*2H  ([Wh|Uz])
  unsigned short* Acat = Wcat + (size_t)kH * 2 * kH;  // B*2H  ([h|z])

  // all fp32->bf16 casts in one pass: 8,912,896 vec4 units / 256 = 34816 blocks
  cast_all<<<34816, 256, 0, stream>>>(x, Wx, Wh, Uz, h, xb, Wxb, Wcat, Acat);

  const int grid = (kB / 256) * (kH / 256);  // 32 * 8 = 256 = 1 block/CU

  // GEMM1: z = tanh(x Wx^T + bx) -> bf16 into Acat[:, H:2H]
  gemm256<0><<<grid, 512, 0, stream>>>(
      xb, Wxb, bx, kB, kIN, Acat + kH, nullptr, 2 * kH, nullptr, 0);

  // GEMM2: u = sigmoid([h|z] [Wh|Uz]^T + bu); out = u*h + (1-u)*z (h,z bf16)
  gemm256<1><<<grid, 512, 0, stream>>>(
      Acat, Wcat, bu, kB, 2 * kH, nullptr, Acat, 2 * kH, out, kH);
}

// Round 13
// 202.104 us; speedup vs baseline: 1.8565x; 1.0203x over previous
//
#include <hip/hip_runtime.h>
#include <hip/hip_bf16.h>
#include <cstdint>
#include <cstddef>

#define DEVFN static __device__ __forceinline__

typedef __attribute__((ext_vector_type(8))) short bf16x8;
typedef __attribute__((ext_vector_type(4))) float f32x4;

static constexpr int kB = 8192;
static constexpr int kIN = 1024;
static constexpr int kH = 2048;

DEVFN unsigned short f32_to_bf16(float f) {
  union { float f; unsigned int u; } v; v.f = f;
  unsigned int x = v.u;
  x += 0x7fffu + ((x >> 16) & 1u);   // round-to-nearest-even
  return (unsigned short)(x >> 16);
}
DEVFN float bf16_to_f32(unsigned short u) {
  union { unsigned int u; float f; } v; v.u = (unsigned int)u << 16;
  return v.f;
}
DEVFN float fast_sigmoid(float x) { return 1.0f / (1.0f + __expf(-x)); }
DEVFN float fast_tanh(float x)    { return 1.0f - 2.0f / (1.0f + __expf(2.0f * x)); }

// one fused cast pass: fp32 -> bf16 for all five panels (vec4 per thread)
__global__ void cast_all(const float* __restrict__ x, const float* __restrict__ Wx,
                         const float* __restrict__ Wh, const float* __restrict__ Uz,
                         const float* __restrict__ h,
                         unsigned short* __restrict__ xb, unsigned short* __restrict__ Wxb,
                         unsigned short* __restrict__ Wcat, unsigned short* __restrict__ Acat) {
  const long i = (long)blockIdx.x * blockDim.x + threadIdx.x;  // vec4 index
  const float* src; unsigned short* dst; int sh, stride, off; long li;
  if (i < 2097152L)      { li = i;            src = x;  dst = xb;   sh = 8; stride = 1024; off = 0; }
  else if (i < 2621440L) { li = i - 2097152L; src = Wx; dst = Wxb;  sh = 8; stride = 1024; off = 0; }
  else if (i < 3670016L) { li = i - 2621440L; src = Wh; dst = Wcat; sh = 9; stride = 4096; off = 0; }
  else if (i < 4718592L) { li = i - 3670016L; src = Uz; dst = Wcat; sh = 9; stride = 4096; off = 2048; }
  else                   { li = i - 4718592L; src = h;  dst = Acat; sh = 9; stride = 4096; off = 0; }
  float4 v = *(const float4*)(src + li * 4);
  const long row = li >> sh;
  const long col = (li & ((1L << sh) - 1)) * 4;
  unsigned short* d = dst + row * stride + off + col;
  ushort4 o;
  o.x = f32_to_bf16(v.x); o.y = f32_to_bf16(v.y);
  o.z = f32_to_bf16(v.z); o.w = f32_to_bf16(v.w);
  *(ushort4*)d = o;
}

typedef const __attribute__((address_space(1))) unsigned int* gptr_t;
typedef __attribute__((address_space(3))) unsigned int* lptr_t;
DEVFN void gload16(const unsigned short* g, unsigned short* l) {
  __builtin_amdgcn_global_load_lds((gptr_t)g, (lptr_t)l, 16, 0, 0);
}

DEVFN void bar() { __builtin_amdgcn_s_barrier(); }
#define VMC0() asm volatile("s_waitcnt vmcnt(0)" ::: "memory")
#define VMC2() asm volatile("s_waitcnt vmcnt(2)" ::: "memory")

// LDS geometry: 8 regions of [128 rows][64 bf16] (16 KiB each) = 128 KiB.
// region = buf*4 + op*2 + half   (op: 0=A, 1=B; half: rows 0-127 / 128-255)
// Swizzle (T2): element col stored at  c ^ ((row&7)*8).
// global_load_lds writes LINEAR; global SOURCE col is pre-swizzled (rule 21).
//
// ONE-PHASE-AHEAD fragment pipeline (best-measured structure, r7/r12 bench):
//   quadrant order per K-tile: Q00,Q01,Q10,Q11.  Single a[4][2] bank,
//   reloaded POST-MFMA at ph2/4/6/8 (WAR-safe); b halves PRE-MFMA ph1/4/5/8.
//   Stage plan: ph1=A1h1(2j+1), ph3=B0'h0, ph4=B0'h1, ph5=A0'h0, ph6=A0'h1,
//   ph7=B1'h0, ph8=B1'h1+A1'h0   (buf0'=2j+2, buf1'=2j+3)
//   Drains: vmcnt(2) at ph3-end (retires buf1') and ph7-end (retires buf0').
//   Loop exits with ~6 staged loads outstanding -> epilogue touching LDS
//   must VMC0()+bar() first.

template<int BUF, int QM>
DEVFN void ldA(bf16x8 (&a)[4][2], const unsigned short* lds, int wm, int lr, int lg) {
  const unsigned short* rg = lds + (size_t)(BUF * 4 + wm) * 8192;
#pragma unroll
  for (int mi = 0; mi < 4; ++mi) {
    const int rl = QM * 64 + mi * 16 + lr;
#pragma unroll
    for (int kk = 0; kk < 2; ++kk) {
      const int kel = (kk * 32 + lg * 8) ^ ((rl & 7) * 8);
      a[mi][kk] = *(const bf16x8*)(rg + rl * 64 + kel);
    }
  }
}

template<int BUF, int QN>
DEVFN void ldB(bf16x8 (&b)[4][2], const unsigned short* lds, int wn, int lr, int lg) {
  const unsigned short* rg = lds + (size_t)(BUF * 4 + 2 + (wn >> 1)) * 8192;
#pragma unroll
  for (int ni = 0; ni < 2; ++ni) {
    const int n = QN * 2 + ni;
    const int cl = (wn & 1) * 64 + n * 16 + lr;
#pragma unroll
    for (int kk = 0; kk < 2; ++kk) {
      const int kel = (kk * 32 + lg * 8) ^ ((cl & 7) * 8);
      b[n][kk] = *(const bf16x8*)(rg + cl * 64 + kel);
    }
  }
}

template<int QM, int QN>
DEVFN void mfmaQ(f32x4 (&acc)[8][4], bf16x8 (&a)[4][2], bf16x8 (&b)[4][2]) {
  __builtin_amdgcn_s_setprio(1);
#pragma unroll
  for (int mi = 0; mi < 4; ++mi)
#pragma unroll
    for (int ni = 0; ni < 2; ++ni)
#pragma unroll
      for (int kk = 0; kk < 2; ++kk)
        acc[QM * 4 + mi][QN * 2 + ni] = __builtin_amdgcn_mfma_f32_16x16x32_bf16(
            a[mi][kk], b[QN * 2 + ni][kk], acc[QM * 4 + mi][QN * 2 + ni], 0, 0, 0);
  __builtin_amdgcn_s_setprio(0);
}

// C = A (MxK) * W^T (W NxK); bias per col.
//  EPI==0: zOut = bf16(tanh(.)) via LDS-repack coalesced store
//  EPI==1: u = sigmoid(.); out = u*h + (1-u)*z, h/z read bf16 from hzBuf
template<int EPI>
__global__ __launch_bounds__(512, 1)
void gemm256(const unsigned short* __restrict__ A,
             const unsigned short* __restrict__ W,
             const float* __restrict__ bias,
             int M, int K,
             unsigned short* __restrict__ zOut,
             const unsigned short* __restrict__ hzBuf, int ldhz,
             float* __restrict__ out, int ldo)
{
  __shared__ unsigned short lds[8][8192];
  unsigned short* L = &lds[0][0];

  const int nTM = M >> 8;
  const int bm = blockIdx.x % nTM, bn = blockIdx.x / nTM;
  const int rowBase = bm << 8, colBase = bn << 8;

  const int t = threadIdx.x;
  const int l = t & 63;
  const int w = t >> 6;
  const int lr = l & 15, lg = l >> 4;
  const int wm = w >> 2, wn = w & 3;

  // staging addresses: thread t covers lds elems [t*8, t*8+8) of each 8KB slab
  const int srow = t >> 3;                       // 0..63
  const int scol = (t & 7) * 8;                  // 0..56
  const int kcSrc = scol ^ ((srow & 7) * 8);     // inverse-swizzled source col
  const unsigned short* gA = A + (size_t)(rowBase + srow) * K + kcSrc;
  const unsigned short* gB = W + (size_t)(colBase + srow) * K + kcSrc;

#define STAGE(BUF, OP, HALF, KT) do {                                          \
    const unsigned short* gs = ((OP) ? gB : gA)                                \
        + (size_t)((HALF) * 128) * K + (size_t)(KT) * 64;                      \
    unsigned short* ld = L + (size_t)((BUF) * 4 + (OP) * 2 + (HALF)) * 8192    \
        + w * 512;                                                             \
    gload16(gs, ld);                                                           \
    gload16(gs + (size_t)64 * K, ld + 4096);                                   \
  } while (0)

  f32x4 acc[8][4] = {};
  bf16x8 a[4][2], b[4][2];

  // prologue: stage buf0=tile0, buf1=tile1 fully; drain; preload a=A0b0, b01=B0b0
  STAGE(0, 1, 0, 0); STAGE(0, 1, 1, 0); STAGE(0, 0, 0, 0); STAGE(0, 0, 1, 0);
  STAGE(1, 1, 0, 1); STAGE(1, 1, 1, 1); STAGE(1, 0, 0, 1); STAGE(1, 0, 1, 1);
  VMC0();
  bar();
  ldA<0, 0>(a, L, wm, lr, lg);
  ldB<0, 0>(b, L, wn, lr, lg);

  const int NP = K >> 7;   // pairs of BK=64 K-tiles
  for (int j = 0; j < NP; ++j) {
    const bool more = (j + 1 < NP);
    const int ktb1 = 2 * j + 1;
    const int kt0n = more ? 2 * j + 2 : 2 * j;      // clamped: benign restage
    const int kt1n = more ? 2 * j + 3 : 2 * j + 1;

    // ph1: Q00-b0.  pre: B1b0 -> b23.  stage A1h1.
    ldB<0, 1>(b, L, wn, lr, lg);
    STAGE(1, 0, 1, ktb1);
    bar();
    mfmaQ<0, 0>(acc, a, b);
    bar();
    // ph2: Q01-b0.  post: a <- A1b0.
    bar();
    mfmaQ<0, 1>(acc, a, b);
    ldA<0, 1>(a, L, wm, lr, lg);
    bar();
    // ph3: Q10-b0.  stage B0'h0.  drain buf1' = vmcnt(2).
    STAGE(0, 1, 0, kt0n);
    bar();
    mfmaQ<1, 0>(acc, a, b);
    VMC2();
    bar();
    // ph4: Q11-b0.  pre: B0b1 -> b01.  stage B0'h1.  post: aLo <- A0b1.
    ldB<1, 0>(b, L, wn, lr, lg);
    STAGE(0, 1, 1, kt0n);
    bar();
    mfmaQ<1, 1>(acc, a, b);
    ldA<1, 0>(a, L, wm, lr, lg);
    bar();
    // ph5: Q00-b1.  pre: B1b1 -> b23.  stage A0'h0.
    ldB<1, 1>(b, L, wn, lr, lg);
    STAGE(0, 0, 0, kt0n);
    bar();
    mfmaQ<0, 0>(acc, a, b);
    bar();
    // ph6: Q01-b1.  stage A0'h1.  post: a <- A1b1.
    STAGE(0, 0, 1, kt0n);
    bar();
    mfmaQ<0, 1>(acc, a, b);
    ldA<1, 1>(a, L, wm, lr, lg);
    bar();
    // ph7: Q10-b1.  stage B1'h0.  drain buf0' = vmcnt(2).
    STAGE(1, 1, 0, kt1n);
    bar();
    mfmaQ<1, 0>(acc, a, b);
    VMC2();
    bar();
    // ph8: Q11-b1.  pre: B0 next pair -> b01.  stage B1'h1 + A1'h0.  post: a <- A0 next.
    ldB<0, 0>(b, L, wn, lr, lg);
    STAGE(1, 1, 1, kt1n);
    STAGE(1, 0, 0, kt1n);
    bar();
    mfmaQ<1, 1>(acc, a, b);
    ldA<0, 0>(a, L, wm, lr, lg);
    bar();
  }
#undef STAGE

  if (EPI == 0) {
    // ---- GEMM1 epilogue: fast tanh + LDS-repack -> coalesced 512B stores ----
    // Loop exits with ~6 outstanding gload_lds writes into staging regions
    // that Z reuses: drain ALL waves' loads before any Z write.
    VMC0();
    bar();
    unsigned short* Z = L;   // 256x256 bf16 = 128 KiB exactly
#pragma unroll
    for (int m = 0; m < 8; ++m) {
      const int rl = wm * 128 + m * 16 + lg * 4;
#pragma unroll
      for (int n = 0; n < 4; ++n) {
        const int cl = wn * 64 + n * 16 + lr;
        const float bs = bias[colBase + cl];
#pragma unroll
        for (int q = 0; q < 4; ++q) {
          const int r = rl + q;
          const int sc = cl ^ ((r & 7) * 8);
          Z[r * 256 + sc] = f32_to_bf16(fast_tanh(acc[m][n][q] + bs));
        }
      }
    }
    bar();
    // store: iteration s, thread t -> 16B; 32 consecutive lanes = one full
    // 512B tile-row segment (fully coalesced).
#pragma unroll
    for (int s = 0; s < 16; ++s) {
      const int gofs = (s * 512 + t) * 8;
      const int row = gofs >> 8;
      const int c0 = gofs & 255;
      const int sc0 = c0 ^ ((row & 7) * 8);
      bf16x8 v = *(const bf16x8*)(Z + row * 256 + sc0);
      *(bf16x8*)(zOut + (size_t)(rowBase + row) * ldhz + colBase + c0) = v;
    }
  } else {
    // C/D layout: col = lane&15, row = (lane>>4)*4 + reg  [HW-verified]
#pragma unroll
    for (int m = 0; m < 8; ++m) {
      const int r0 = rowBase + wm * 128 + m * 16 + lg * 4;
#pragma unroll
      for (int n = 0; n < 4; ++n) {
        const int c = colBase + wn * 64 + n * 16 + lr;
        const float bs = bias[c];
#pragma unroll
        for (int q = 0; q < 4; ++q) {
          const int r = r0 + q;
          const float pre = acc[m][n][q] + bs;
          const float u = fast_sigmoid(pre);
          const float hv = bf16_to_f32(hzBuf[(size_t)r * ldhz + c]);
          const float zv = bf16_to_f32(hzBuf[(size_t)r * ldhz + 2048 + c]);
          out[(size_t)r * ldo + c] = u * hv + (1.0f - u) * zv;
        }
      }
    }
  }
}

extern "C" void kernel_launch(void* const* d_in, const int* in_sizes, int n_in,
                              void* d_out, int out_size, void* d_ws, size_t ws_size,
                              hipStream_t stream) {
  const float* h  = (const float*)d_in[0];   // (B,H)
  const float* x  = (const float*)d_in[1];   // (B,IN)
  const float* Wx = (const float*)d_in[2];   // (H,IN)
  const float* bx = (const float*)d_in[3];   // (H)
  const float* Wh = (const float*)d_in[4];   // (H,H)
  const float* Uz = (const float*)d_in[5];   // (H,H)
  const float* bu = (const float*)d_in[6];   // (H)
  float* out = (float*)d_out;

  unsigned short* ws   = (unsigned short*)d_ws;
  unsigned short* xb   = ws;                          // B*IN
  unsigned short* Wxb  = xb + (size_t)kB * kIN;       // H*IN
  unsigned short* Wcat = Wxb + (size_t)kH * kIN;      // H*2H  ([Wh|Uz])
  unsigned short* Acat = Wcat + (size_t)kH * 2 * kH;  // B*2H  ([h|z])

  // all fp32->bf16 casts in one pass: 8,912,896 vec4 units / 256 = 34816 blocks
  cast_all<<<34816, 256, 0, stream>>>(x, Wx, Wh, Uz, h, xb, Wxb, Wcat, Acat);

  const int grid = (kB / 256) * (kH / 256);  // 32 * 8 = 256 = 1 block/CU

  // GEMM1: z = tanh(x Wx^T + bx) -> bf16 into Acat[:, H:2H]
  gemm256<0><<<grid, 512, 0, stream>>>(
      xb, Wxb, bx, kB, kIN, Acat + kH, nullptr, 2 * kH, nullptr, 0);

  // GEMM2: u = sigmoid([h|z] [Wh|Uz]^T + bu); out = u*h + (1-u)*z (h,z bf16)
  gemm256<1><<<grid, 512, 0, stream>>>(
      Acat, Wcat, bu, kB, 2 * kH, nullptr, Acat, 2 * kH, out, kH);
}

// Round 14
// 202.090 us; speedup vs baseline: 1.8566x; 1.0001x over previous
//
#include <hip/hip_runtime.h>
#include <hip/hip_bf16.h>
#include <cstdint>
#include <cstddef>

#define DEVFN static __device__ __forceinline__

typedef __attribute__((ext_vector_type(8))) short bf16x8;
typedef __attribute__((ext_vector_type(4))) float f32x4;

static constexpr int kB = 8192;
static constexpr int kIN = 1024;
static constexpr int kH = 2048;

DEVFN unsigned short f32_to_bf16(float f) {
  union { float f; unsigned int u; } v; v.f = f;
  unsigned int x = v.u;
  x += 0x7fffu + ((x >> 16) & 1u);   // round-to-nearest-even
  return (unsigned short)(x >> 16);
}
DEVFN float bf16_to_f32(unsigned short u) {
  union { unsigned int u; float f; } v; v.u = (unsigned int)u << 16;
  return v.f;
}
DEVFN float fast_sigmoid(float x) { return 1.0f / (1.0f + __expf(-x)); }
DEVFN float fast_tanh(float x)    { return 1.0f - 2.0f / (1.0f + __expf(2.0f * x)); }

// fused cast pass: fp32 -> bf16 for x, Wx, Wh, Uz (h is cast inside GEMM1)
__global__ void cast_all(const float* __restrict__ x, const float* __restrict__ Wx,
                         const float* __restrict__ Wh, const float* __restrict__ Uz,
                         unsigned short* __restrict__ xb, unsigned short* __restrict__ Wxb,
                         unsigned short* __restrict__ Wcat) {
  const long i = (long)blockIdx.x * blockDim.x + threadIdx.x;  // vec4 index
  const float* src; unsigned short* dst; int sh, stride, off; long li;
  if (i < 2097152L)      { li = i;            src = x;  dst = xb;   sh = 8; stride = 1024; off = 0; }
  else if (i < 2621440L) { li = i - 2097152L; src = Wx; dst = Wxb;  sh = 8; stride = 1024; off = 0; }
  else if (i < 3670016L) { li = i - 2621440L; src = Wh; dst = Wcat; sh = 9; stride = 4096; off = 0; }
  else                   { li = i - 3670016L; src = Uz; dst = Wcat; sh = 9; stride = 4096; off = 2048; }
  float4 v = *(const float4*)(src + li * 4);
  const long row = li >> sh;
  const long col = (li & ((1L << sh) - 1)) * 4;
  unsigned short* d = dst + row * stride + off + col;
  ushort4 o;
  o.x = f32_to_bf16(v.x); o.y = f32_to_bf16(v.y);
  o.z = f32_to_bf16(v.z); o.w = f32_to_bf16(v.w);
  *(ushort4*)d = o;
}

typedef const __attribute__((address_space(1))) unsigned int* gptr_t;
typedef __attribute__((address_space(3))) unsigned int* lptr_t;
DEVFN void gload16(const unsigned short* g, unsigned short* l) {
  __builtin_amdgcn_global_load_lds((gptr_t)g, (lptr_t)l, 16, 0, 0);
}

DEVFN void bar() { __builtin_amdgcn_s_barrier(); }
#define VMC0()  asm volatile("s_waitcnt vmcnt(0)" ::: "memory")
#define VMC2()  asm volatile("s_waitcnt vmcnt(2)" ::: "memory")
#define VMC10() asm volatile("s_waitcnt vmcnt(10)" ::: "memory")

// LDS geometry: 8 regions of [128 rows][64 bf16] (16 KiB each) = 128 KiB.
// region = buf*4 + op*2 + half   (op: 0=A, 1=B; half: rows 0-127 / 128-255)
// Swizzle (T2): element col stored at  c ^ ((row&7)*8).
// global_load_lds writes LINEAR; global SOURCE col is pre-swizzled (rule 21).
//
// ONE-PHASE-AHEAD fragment pipeline (best-measured structure, r7/r12/r13):
//   Stage plan: ph1=A1h1(2j+1), ph3=B0'h0, ph4=B0'h1, ph5=A0'h0, ph6=A0'h1,
//   ph7=B1'h0, ph8=B1'h1+A1'h0   (buf0'=2j+2, buf1'=2j+3)
//
// GEMM1-only fused h-cast (EPI==0): per pair j, 4 coalesced float4 loads of
// the block's h-slice issued at ph1 START (before ph1's stage, so the
// compiler's pre-convert wait is a counted vmcnt, not a drain); convert +
// 2x16B store in ph2 (the stage-free phase).  vm-queue order per pair:
// {loads(4), ph1 stage(2), stores(2), ph3 stage(2)} -> ph3 drain becomes
// vmcnt(10) (retires exactly prev ph7+ph8 = buf1', ages >=4 phases); ph7
// drain stays vmcnt(2) (also retires the cast ops, then ages >=4).
// 8 pairs x 32 rows = the block's full 256x256 h-slice.

template<int BUF, int QM>
DEVFN void ldA(bf16x8 (&a)[4][2], const unsigned short* lds, int wm, int lr, int lg) {
  const unsigned short* rg = lds + (size_t)(BUF * 4 + wm) * 8192;
#pragma unroll
  for (int mi = 0; mi < 4; ++mi) {
    const int rl = QM * 64 + mi * 16 + lr;
#pragma unroll
    for (int kk = 0; kk < 2; ++kk) {
      const int kel = (kk * 32 + lg * 8) ^ ((rl & 7) * 8);
      a[mi][kk] = *(const bf16x8*)(rg + rl * 64 + kel);
    }
  }
}

template<int BUF, int QN>
DEVFN void ldB(bf16x8 (&b)[4][2], const unsigned short* lds, int wn, int lr, int lg) {
  const unsigned short* rg = lds + (size_t)(BUF * 4 + 2 + (wn >> 1)) * 8192;
#pragma unroll
  for (int ni = 0; ni < 2; ++ni) {
    const int n = QN * 2 + ni;
    const int cl = (wn & 1) * 64 + n * 16 + lr;
#pragma unroll
    for (int kk = 0; kk < 2; ++kk) {
      const int kel = (kk * 32 + lg * 8) ^ ((cl & 7) * 8);
      b[n][kk] = *(const bf16x8*)(rg + cl * 64 + kel);
    }
  }
}

template<int QM, int QN>
DEVFN void mfmaQ(f32x4 (&acc)[8][4], bf16x8 (&a)[4][2], bf16x8 (&b)[4][2]) {
  __builtin_amdgcn_s_setprio(1);
#pragma unroll
  for (int mi = 0; mi < 4; ++mi)
#pragma unroll
    for (int ni = 0; ni < 2; ++ni)
#pragma unroll
      for (int kk = 0; kk < 2; ++kk)
        acc[QM * 4 + mi][QN * 2 + ni] = __builtin_amdgcn_mfma_f32_16x16x32_bf16(
            a[mi][kk], b[QN * 2 + ni][kk], acc[QM * 4 + mi][QN * 2 + ni], 0, 0, 0);
  __builtin_amdgcn_s_setprio(0);
}

// C = A (MxK) * W^T (W NxK); bias per col.
//  EPI==0: zOut = bf16(tanh(.)) via LDS-repack; also casts h slice (hSrc->hDst)
//  EPI==1: u = sigmoid(.); out = u*h + (1-u)*z, h/z read bf16 from hzBuf
template<int EPI>
__global__ __launch_bounds__(512, 1)
void gemm256(const unsigned short* __restrict__ A,
             const unsigned short* __restrict__ W,
             const float* __restrict__ bias,
             int M, int K,
             unsigned short* __restrict__ zOut,
             const unsigned short* __restrict__ hzBuf, int ldhz,
             float* __restrict__ out, int ldo,
             const float* __restrict__ hSrc,
             unsigned short* __restrict__ hDst)
{
  __shared__ unsigned short lds[8][8192];
  unsigned short* L = &lds[0][0];

  const int nTM = M >> 8;
  const int bm = blockIdx.x % nTM, bn = blockIdx.x / nTM;
  const int rowBase = bm << 8, colBase = bn << 8;

  const int t = threadIdx.x;
  const int l = t & 63;
  const int w = t >> 6;
  const int lr = l & 15, lg = l >> 4;
  const int wm = w >> 2, wn = w & 3;

  // staging addresses: thread t covers lds elems [t*8, t*8+8) of each 8KB slab
  const int srow = t >> 3;                       // 0..63
  const int scol = (t & 7) * 8;                  // 0..56
  const int kcSrc = scol ^ ((srow & 7) * 8);     // inverse-swizzled source col
  const unsigned short* gA = A + (size_t)(rowBase + srow) * K + kcSrc;
  const unsigned short* gB = W + (size_t)(colBase + srow) * K + kcSrc;

  // fused h-cast addressing (EPI==0): thread t -> row rowBase+j*32+(t>>4),
  // cols colBase+(t&15)*16 .. +16  (16 lanes x 64B = coalesced 1KB)
  const int hr0 = rowBase + (t >> 4);
  const int hcol = colBase + (t & 15) * 16;
  const float* hp = (EPI == 0) ? hSrc + (size_t)hr0 * 2048 + hcol : nullptr;
  unsigned short* hq = (EPI == 0) ? hDst + (size_t)hr0 * 4096 + hcol : nullptr;

#define STAGE(BUF, OP, HALF, KT) do {                                          \
    const unsigned short* gs = ((OP) ? gB : gA)                                \
        + (size_t)((HALF) * 128) * K + (size_t)(KT) * 64;                      \
    unsigned short* ld = L + (size_t)((BUF) * 4 + (OP) * 2 + (HALF)) * 8192    \
        + w * 512;                                                             \
    gload16(gs, ld);                                                           \
    gload16(gs + (size_t)64 * K, ld + 4096);                                   \
  } while (0)

  f32x4 acc[8][4] = {};
  bf16x8 a[4][2], b[4][2];

  // prologue: stage buf0=tile0, buf1=tile1 fully; drain; preload a=A0b0, b01=B0b0
  STAGE(0, 1, 0, 0); STAGE(0, 1, 1, 0); STAGE(0, 0, 0, 0); STAGE(0, 0, 1, 0);
  STAGE(1, 1, 0, 1); STAGE(1, 1, 1, 1); STAGE(1, 0, 0, 1); STAGE(1, 0, 1, 1);
  VMC0();
  bar();
  ldA<0, 0>(a, L, wm, lr, lg);
  ldB<0, 0>(b, L, wn, lr, lg);

  const int NP = K >> 7;   // pairs of BK=64 K-tiles
  for (int j = 0; j < NP; ++j) {
    const bool more = (j + 1 < NP);
    const int ktb1 = 2 * j + 1;
    const int kt0n = more ? 2 * j + 2 : 2 * j;      // clamped: benign restage
    const int kt1n = more ? 2 * j + 3 : 2 * j + 1;

    // ph1: Q00-b0.  [EPI0: issue h-cast loads FIRST so later wait is counted]
    //      pre: B1b0 -> b23.  stage A1h1.
    float4 v0, v1, v2, v3;
    if (EPI == 0) {
      v0 = *(const float4*)(hp);
      v1 = *(const float4*)(hp + 4);
      v2 = *(const float4*)(hp + 8);
      v3 = *(const float4*)(hp + 12);
    }
    ldB<0, 1>(b, L, wn, lr, lg);
    STAGE(1, 0, 1, ktb1);
    bar();
    mfmaQ<0, 0>(acc, a, b);
    bar();
    // ph2: Q01-b0.  post: a <- A1b0.  [EPI0: convert + store h slice]
    bar();
    mfmaQ<0, 1>(acc, a, b);
    ldA<0, 1>(a, L, wm, lr, lg);
    if (EPI == 0) {
      bf16x8 q0, q1;
      q0[0] = (short)f32_to_bf16(v0.x); q0[1] = (short)f32_to_bf16(v0.y);
      q0[2] = (short)f32_to_bf16(v0.z); q0[3] = (short)f32_to_bf16(v0.w);
      q0[4] = (short)f32_to_bf16(v1.x); q0[5] = (short)f32_to_bf16(v1.y);
      q0[6] = (short)f32_to_bf16(v1.z); q0[7] = (short)f32_to_bf16(v1.w);
      q1[0] = (short)f32_to_bf16(v2.x); q1[1] = (short)f32_to_bf16(v2.y);
      q1[2] = (short)f32_to_bf16(v2.z); q1[3] = (short)f32_to_bf16(v2.w);
      q1[4] = (short)f32_to_bf16(v3.x); q1[5] = (short)f32_to_bf16(v3.y);
      q1[6] = (short)f32_to_bf16(v3.z); q1[7] = (short)f32_to_bf16(v3.w);
      *(bf16x8*)(hq) = q0;
      *(bf16x8*)(hq + 8) = q1;
      hp += 32 * 2048;
      hq += 32 * 4096;
    }
    bar();
    // ph3: Q10-b0.  stage B0'h0.  drain buf1' (prev ph7/ph8):
    //      EPI0 = vmcnt(10) [leaves loads(4)+ph1(2)+stores(2)+ph3(2)],
    //      EPI1 = vmcnt(2)  [leaves ph3's 2].
    STAGE(0, 1, 0, kt0n);
    bar();
    mfmaQ<1, 0>(acc, a, b);
    if (EPI == 0) { VMC10(); } else { VMC2(); }
    bar();
    // ph4: Q11-b0.  pre: B0b1 -> b01.  stage B0'h1.  post: aLo <- A0b1.
    ldB<1, 0>(b, L, wn, lr, lg);
    STAGE(0, 1, 1, kt0n);
    bar();
    mfmaQ<1, 1>(acc, a, b);
    ldA<1, 0>(a, L, wm, lr, lg);
    bar();
    // ph5: Q00-b1.  pre: B1b1 -> b23.  stage A0'h0.
    ldB<1, 1>(b, L, wn, lr, lg);
    STAGE(0, 0, 0, kt0n);
    bar();
    mfmaQ<0, 0>(acc, a, b);
    bar();
    // ph6: Q01-b1.  stage A0'h1.  post: a <- A1b1.
    STAGE(0, 0, 1, kt0n);
    bar();
    mfmaQ<0, 1>(acc, a, b);
    ldA<1, 1>(a, L, wm, lr, lg);
    bar();
    // ph7: Q10-b1.  stage B1'h0.  drain buf0' (ph3..ph6) = vmcnt(2)
    //      (also retires this pair's cast loads/stores, ages >=4 phases).
    STAGE(1, 1, 0, kt1n);
    bar();
    mfmaQ<1, 0>(acc, a, b);
    VMC2();
    bar();
    // ph8: Q11-b1.  pre: B0 next pair -> b01.  stage B1'h1 + A1'h0.  post: a <- A0 next.
    ldB<0, 0>(b, L, wn, lr, lg);
    STAGE(1, 1, 1, kt1n);
    STAGE(1, 0, 0, kt1n);
    bar();
    mfmaQ<1, 1>(acc, a, b);
    ldA<0, 0>(a, L, wm, lr, lg);
    bar();
  }
#undef STAGE

  if (EPI == 0) {
    // ---- GEMM1 epilogue: fast tanh + LDS-repack -> coalesced 512B stores ----
    // Drain outstanding gload_lds writes into staging regions Z reuses.
    VMC0();
    bar();
    unsigned short* Z = L;   // 256x256 bf16 = 128 KiB exactly
#pragma unroll
    for (int m = 0; m < 8; ++m) {
      const int rl = wm * 128 + m * 16 + lg * 4;
#pragma unroll
      for (int n = 0; n < 4; ++n) {
        const int cl = wn * 64 + n * 16 + lr;
        const float bs = bias[colBase + cl];
#pragma unroll
        for (int q = 0; q < 4; ++q) {
          const int r = rl + q;
          const int sc = cl ^ ((r & 7) * 8);
          Z[r * 256 + sc] = f32_to_bf16(fast_tanh(acc[m][n][q] + bs));
        }
      }
    }
    bar();
#pragma unroll
    for (int s = 0; s < 16; ++s) {
      const int gofs = (s * 512 + t) * 8;
      const int row = gofs >> 8;
      const int c0 = gofs & 255;
      const int sc0 = c0 ^ ((row & 7) * 8);
      bf16x8 v = *(const bf16x8*)(Z + row * 256 + sc0);
      *(bf16x8*)(zOut + (size_t)(rowBase + row) * ldhz + colBase + c0) = v;
    }
  } else {
    // C/D layout: col = lane&15, row = (lane>>4)*4 + reg  [HW-verified]
#pragma unroll
    for (int m = 0; m < 8; ++m) {
      const int r0 = rowBase + wm * 128 + m * 16 + lg * 4;
#pragma unroll
      for (int n = 0; n < 4; ++n) {
        const int c = colBase + wn * 64 + n * 16 + lr;
        const float bs = bias[c];
#pragma unroll
        for (int q = 0; q < 4; ++q) {
          const int r = r0 + q;
          const float pre = acc[m][n][q] + bs;
          const float u = fast_sigmoid(pre);
          const float hv = bf16_to_f32(hzBuf[(size_t)r * ldhz + c]);
          const float zv = bf16_to_f32(hzBuf[(size_t)r * ldhz + 2048 + c]);
          out[(size_t)r * ldo + c] = u * hv + (1.0f - u) * zv;
        }
      }
    }
  }
}

extern "C" void kernel_launch(void* const* d_in, const int* in_sizes, int n_in,
                              void* d_out, int out_size, void* d_ws, size_t ws_size,
                              hipStream_t stream) {
  const float* h  = (const float*)d_in[0];   // (B,H)
  const float* x  = (const float*)d_in[1];   // (B,IN)
  const float* Wx = (const float*)d_in[2];   // (H,IN)
  const float* bx = (const float*)d_in[3];   // (H)
  const float* Wh = (const float*)d_in[4];   // (H,H)
  const float* Uz = (const float*)d_in[5];   // (H,H)
  const float* bu = (const float*)d_in[6];   // (H)
  float* out = (float*)d_out;

  unsigned short* ws   = (unsigned short*)d_ws;
  unsigned short* xb   = ws;                          // B*IN
  unsigned short* Wxb  = xb + (size_t)kB * kIN;       // H*IN
  unsigned short* Wcat = Wxb + (size_t)kH * kIN;      // H*2H  ([Wh|Uz])
  unsigned short* Acat = Wcat + (size_t)kH * 2 * kH;  // B*2H  ([h|z])

  // x, Wx, Wh, Uz casts: 4,718,592 vec4 units / 256 = 18432 blocks
  cast_all<<<18432, 256, 0, stream>>>(x, Wx, Wh, Uz, xb, Wxb, Wcat);

  const int grid = (kB / 256) * (kH / 256);  // 32 * 8 = 256 = 1 block/CU

  // GEMM1: z = tanh(x Wx^T + bx) -> bf16 into Acat[:, H:2H];
  //        also casts h (fp32) -> Acat[:, 0:H] fused into the K-loop.
  gemm256<0><<<grid, 512, 0, stream>>>(
      xb, Wxb, bx, kB, kIN, Acat + kH, nullptr, 2 * kH, nullptr, 0, h, Acat);

  // GEMM2: u = sigmoid([h|z] [Wh|Uz]^T + bu); out = u*h + (1-u)*z (h,z bf16)
  gemm256<1><<<grid, 512, 0, stream>>>(
      Acat, Wcat, bu, kB, 2 * kH, nullptr, Acat, 2 * kH, out, kH, nullptr, nullptr);
}